// Round 16
// baseline (43.690 us; speedup 1.0000x reference)
//
#include <hip/hip_runtime.h>

#define DIM 128
#define NHEAD 64
#define NROT 8128
#define NSEG 7
#define KAC 136                 // A LDS k-stride (u16): 272B rows -> 2-way banks

typedef float f4 __attribute__((ext_vector_type(4)));
typedef short bf8 __attribute__((ext_vector_type(8)));
typedef unsigned short u16;

// G=32 pivot segments (R15-verified tables). Segment s: pivots {a0..a0+31},
// trailing rows [j0, j0+nj). n = 32+nj. Chunk-0 segments carry 496 intra rots.
__device__ const int C_A0[NSEG]    = {0,0,0,32,32,64,96};
__device__ const int C_J0[NSEG]    = {32,64,96,64,96,96,128};
__device__ const int C_NJ[NSEG]    = {32,32,32,32,32,32,0};
__device__ const int C_N[NSEG]     = {64,64,64,64,64,64,32};
__device__ const int C_INTRA[NSEG] = {1,0,0,1,0,1,1};
__device__ const int C_RB[NSEG]    = {0,8192,16384,24576,32768,40960,49152}; // u16 units

// M LDS layout per segment (u16 idx rel. RB), col XOR-swizzled by row:
//   pivot  h: rl*n + (col^sw)        l: +32*n        (rl = 0..31)
//   trail  h: 64*n + r*2n + (col^sw) l: +n           (rl = 32+r)
//   sw = (rl & (n==32?3:7)) << 3   [16B-granule XOR -> 2-way banks everywhere]
// cs overlay (phase 1a only): intra 992 f32 at byte RB*2 (under pivot area);
// trailing row r: 64 f32 at byte RB*2 + 128n + 256r == M trail row r's slot.

__device__ __forceinline__ void sincos_poly(float x, float& sn, float& cn) {
    float x2 = x * x;
    sn = x * fmaf(x2, fmaf(x2, 8.33333333e-3f, -1.66666667e-1f), 1.0f);
    cn = fmaf(x2, fmaf(x2, 4.16666667e-2f, -0.5f), 1.0f);
}
__device__ __forceinline__ u16 f2bf(float v) {
    unsigned b = __float_as_uint(v);
    b += 0x7FFF + ((b >> 16) & 1);
    return (u16)(b >> 16);
}
__device__ __forceinline__ float bf2f(u16 h) {
    return __uint_as_float(((unsigned)h) << 16);
}
__device__ __forceinline__ int tri_base(int i) { return (i * (2 * DIM - 1 - i)) >> 1; }

__global__ __launch_bounds__(512, 2)
void givens_fused(const float* __restrict__ th_all, float* __restrict__ out)
{
    __shared__ u16 Ml[51200];            // M bf16-pair, all 7 segments (102400 B)
    __shared__ u16 Ah[32][KAC];          // A high (8704 B)
    __shared__ u16 Al[32][KAC];          // A low  (8704 B)

    const int tid  = threadIdx.x;
    const int lane = tid & 63;
    const int w    = tid >> 6;
    const int head = blockIdx.x & 63;
    const int q    = blockIdx.x >> 6;    // 32-col quarter
    const float* __restrict__ th = th_all + head * NROT;

    // ---------- Phase 1a: per-wave theta -> cos/sin staging (cs overlay) ----------
    if (w < NSEG) {
        const int s = w;
        const int a0 = C_A0[s], j0 = C_J0[s], nj = C_NJ[s], n = C_N[s];
        const bool intra = C_INTRA[s] != 0;
        const int ne = 32 * nj;
        const int d1 = j0 - a0 - 1;
        float* csb = (float*)&Ml[C_RB[s]];
        float* cst = csb + 32 * n;

        float thx[16];
        #pragma unroll
        for (int it = 0; it < 16; ++it)
            if (it * 64 < ne) {
                int e = lane + it * 64;
                int t = e & 31, r = e >> 5;
                thx[it] = th[tri_base(a0 + t) + d1 + r - t];
            }
        float thi[8];
        #pragma unroll
        for (int it = 0; it < 8; ++it) {
            int e = lane + it * 64;
            if (intra && e < 496) {
                int t1 = 0, rem = e;
                while (rem >= 31 - t1) { rem -= 31 - t1; ++t1; }
                thi[it] = th[tri_base(a0 + t1) + rem];   // off = t2-t1-1 = rem
            }
        }
        #pragma unroll
        for (int it = 0; it < 16; ++it)
            if (it * 64 < ne) {
                int e = lane + it * 64;
                float sn, cn; sincos_poly(thx[it], sn, cn);
                cst[2 * e] = cn; cst[2 * e + 1] = sn;
            }
        #pragma unroll
        for (int it = 0; it < 8; ++it) {
            int e = lane + it * 64;
            if (intra && e < 496) {
                float sn, cn; sincos_poly(thi[it], sn, cn);
                csb[2 * e] = cn; csb[2 * e + 1] = sn;
            }
        }
    }
    __syncthreads();

    // ---------- Phase 1b: Q-less register chain -> M in LDS ----------
    if (w < NSEG) {
        const int s = w;
        const int a0 = C_A0[s], nj = C_NJ[s], n = C_N[s], RB = C_RB[s];
        const bool intra = C_INTRA[s] != 0;
        const int msk = (n == 32) ? 3 : 7;
        const float* csb = (const float*)&Ml[RB];
        const float* cst = csb + 32 * n;
        const bool cact = lane < n;

        float p[32];
        #pragma unroll
        for (int t = 0; t < 32; ++t) p[t] = (lane == t) ? 1.0f : 0.0f;

        if (intra) {                     // 496 pivot-pivot rotations
            f4 cc; int idx = 0;
            #pragma unroll
            for (int t1 = 0; t1 < 31; ++t1) {
                #pragma unroll
                for (int t2 = t1 + 1; t2 < 32; ++t2) {
                    float c, sn;
                    if ((idx & 1) == 0) { cc = *(const f4*)&csb[2 * idx]; c = cc.x; sn = cc.y; }
                    else                { c = cc.z; sn = cc.w; }
                    float pa = p[t1];
                    p[t1] = fmaf(c, pa,    sn * p[t2]);
                    p[t2] = fmaf(c, p[t2], -(sn * pa));
                    ++idx;
                }
            }
        }

        if (nj > 0) {
            const int jv = lane - 32;
            #pragma unroll 2
            for (int r = 0; r < nj; ++r) {
                const f4* c4 = (const f4*)(cst + 64 * r);
                f4 qv[16];
                #pragma unroll
                for (int i = 0; i < 16; ++i) qv[i] = c4[i];
                float v = (r == jv) ? 1.0f : 0.0f;
                #pragma unroll
                for (int t = 0; t < 32; t += 2) {
                    f4 qq = qv[t >> 1];
                    { float pv = p[t];     float nv = fmaf(qq.x, v, -(qq.y * pv));
                      p[t]     = fmaf(qq.y, v, qq.x * pv); v = nv; }
                    { float pv = p[t + 1]; float nv = fmaf(qq.z, v, -(qq.w * pv));
                      p[t + 1] = fmaf(qq.w, v, qq.z * pv); v = nv; }
                }
                if (cact) {              // M row lands in its own dead cs slot
                    u16 h = f2bf(v), l = f2bf(v - bf2f(h));
                    int sw = ((32 + r) & msk) << 3;
                    int hi = RB + 64 * n + r * 2 * n + (lane ^ sw);
                    Ml[hi] = h; Ml[hi + n] = l;
                }
            }
        }
        if (cact) {                      // pivot rows (intra-cs area is dead)
            #pragma unroll
            for (int t = 0; t < 32; ++t) {
                u16 h = f2bf(p[t]), l = f2bf(p[t] - bf2f(h));
                int sw = (t & msk) << 3;
                int hi = RB + t * n + (lane ^ sw);
                Ml[hi] = h; Ml[hi + 32 * n] = l;
            }
        }
    }
    __syncthreads();

    // ---------- Phase 1c: A init (embedded M0 slice for this quarter) ----------
    for (int i = tid; i < 32 * KAC; i += 512) {
        int c = i / KAC, k = i - c * KAC;
        int cg = q * 32 + c;
        u16 h = 0, l = 0;
        if (k < 64) {
            if (cg < 64) {               // M0: segment 0 (RB=0, n=64)
                int sw = (k & 7) << 3;
                if (k < 32) { int hi = k * 64 + (cg ^ sw);
                              h = Ml[hi]; l = Ml[hi + 2048]; }
                else        { int hi = 4096 + (k - 32) * 128 + (cg ^ sw);
                              h = Ml[hi]; l = Ml[hi + 64]; }
            }
        } else if (k < 128) {
            h = (k == cg) ? (u16)0x3F80 : (u16)0;
        }
        Ah[c][k] = h; Al[c][k] = l;
    }
    __syncthreads();

    // ---------- Phase 2: 6 serial MFMA composes (all-LDS operands) ----------
    const int fr = lane & 15;
    const int fk = (lane >> 4) * 8;
    const int r4 = (lane >> 4) * 4;

    #pragma unroll 1
    for (int s = 1; s < NSEG; ++s) {
        const int a0 = C_A0[s], j0 = C_J0[s], n = C_N[s], RB = C_RB[s];
        const int msk = (n == 32) ? 3 : 7;
        const int nrt = n >> 4;
        const bool act = w < nrt * 2;
        const int rt = w >> 1, ct = w & 1;

        f4 acc = {0, 0, 0, 0};
        if (act) {
            auto mload = [&](int rl, int kc, bf8& mh, bf8& ml) {
                int sw = (rl & msk) << 3;
                int hi;
                if (rl < 32) { hi = RB + rl * n + (kc ^ sw);
                               mh = *(const bf8*)&Ml[hi];
                               ml = *(const bf8*)&Ml[hi + 32 * n]; }
                else         { hi = RB + 64 * n + (rl - 32) * 2 * n + (kc ^ sw);
                               mh = *(const bf8*)&Ml[hi];
                               ml = *(const bf8*)&Ml[hi + n]; }
            };
            const int rA = rt * 16 + fr;
            const int c  = ct * 16 + fr;
            bf8 mh0, ml0;
            mload(rA, fk, mh0, ml0);
            bf8 bh0 = *(const bf8*)&Ah[c][a0 + fk];
            bf8 bl0 = *(const bf8*)&Al[c][a0 + fk];
            acc = __builtin_amdgcn_mfma_f32_16x16x32_bf16(mh0, bh0, acc, 0, 0, 0);
            acc = __builtin_amdgcn_mfma_f32_16x16x32_bf16(mh0, bl0, acc, 0, 0, 0);
            acc = __builtin_amdgcn_mfma_f32_16x16x32_bf16(ml0, bh0, acc, 0, 0, 0);
            acc = __builtin_amdgcn_mfma_f32_16x16x32_bf16(ml0, bl0, acc, 0, 0, 0);
            if (n == 64) {
                bf8 mh1, ml1;
                mload(rA, 32 + fk, mh1, ml1);
                bf8 bh1 = *(const bf8*)&Ah[c][j0 + fk];
                bf8 bl1 = *(const bf8*)&Al[c][j0 + fk];
                acc = __builtin_amdgcn_mfma_f32_16x16x32_bf16(mh1, bh1, acc, 0, 0, 0);
                acc = __builtin_amdgcn_mfma_f32_16x16x32_bf16(mh1, bl1, acc, 0, 0, 0);
                acc = __builtin_amdgcn_mfma_f32_16x16x32_bf16(ml1, bh1, acc, 0, 0, 0);
                acc = __builtin_amdgcn_mfma_f32_16x16x32_bf16(ml1, bl1, acc, 0, 0, 0);
            }
        }
        __syncthreads();                 // all reads of old A complete

        if (act) {
            const int rowq = rt * 16 + r4;
            const int rg = (rowq < 32) ? (a0 + rowq) : (j0 + rowq - 32);
            const int c  = ct * 16 + fr;
            float v0 = acc[0], v1 = acc[1], v2 = acc[2], v3 = acc[3];
            u16 h0 = f2bf(v0), h1 = f2bf(v1), h2 = f2bf(v2), h3 = f2bf(v3);
            u16 l0 = f2bf(v0 - bf2f(h0)), l1 = f2bf(v1 - bf2f(h1));
            u16 l2 = f2bf(v2 - bf2f(h2)), l3 = f2bf(v3 - bf2f(h3));
            ushort4 hv; hv.x = h0; hv.y = h1; hv.z = h2; hv.w = h3;
            ushort4 lv; lv.x = l0; lv.y = l1; lv.z = l2; lv.w = l3;
            *(ushort4*)&Ah[c][rg] = hv;
            *(ushort4*)&Al[c][rg] = lv;
        }
        __syncthreads();                 // new A visible
    }

    // ---------- Output: Q = Ah + Al (coalesced 128B rows per 32 lanes) ----------
    {
        float* o = out + (size_t)head * (DIM * DIM) + q * 32;
        for (int i = tid; i < 32 * DIM; i += 512) {
            int c = i & 31, r = i >> 5;
            o[r * DIM + c] = bf2f(Ah[c][r]) + bf2f(Al[c][r]);
        }
    }
}

extern "C" void kernel_launch(void* const* d_in, const int* in_sizes, int n_in,
                              void* d_out, int out_size, void* d_ws, size_t ws_size,
                              hipStream_t stream) {
    const float* thetas = (const float*)d_in[0];
    float* out = (float*)d_out;
    // Fully fused: no workspace needed, single launch.
    givens_fused<<<dim3(4 * NHEAD), dim3(512), 0, stream>>>(thetas, out);
}

// Round 17
// 39.651 us; speedup vs baseline: 1.1019x; 1.1019x over previous
//
#include <hip/hip_runtime.h>

#define DIM 128
#define NHEAD 64
#define NROT 8128
#define NSEG 7
#define MHEAD7 25600           // u16 elements per head per array (h or l)
#define KAC 136                // A LDS k-stride (u16): 272B rows -> 2-way banks
#define CSROWS 64              // mono fallback staging

typedef float f4 __attribute__((ext_vector_type(4)));
typedef short bf8 __attribute__((ext_vector_type(8)));
typedef unsigned short u16;

// G=32 pivot segments (R15-verified). Segment s: pivots {a0..a0+31},
// trailing rows [j0, j0+nj). n = 32+nj. INTRA segments carry 496 intra rots.
__device__ const int C_A0[NSEG]    = {0,0,0,32,32,64,96};
__device__ const int C_J0[NSEG]    = {32,64,96,64,96,96,128};
__device__ const int C_NJ[NSEG]    = {32,32,32,32,32,32,0};
__device__ const int C_N[NSEG]     = {64,64,64,64,64,64,32};
__device__ const int C_OFF[NSEG]   = {0,4096,8192,12288,16384,20480,24576};
__device__ const int C_INTRA[NSEG] = {1,0,0,1,0,1,1};
__device__ const int C_LB[NSEG]    = {0,8192,16384,24576,32768,40960,49152}; // LDS u16 base (h; l at +n*n)

__device__ __forceinline__ void sincos_poly(float x, float& sn, float& cn) {
    float x2 = x * x;
    sn = x * fmaf(x2, fmaf(x2, 8.33333333e-3f, -1.66666667e-1f), 1.0f);
    cn = fmaf(x2, fmaf(x2, 4.16666667e-2f, -0.5f), 1.0f);
}
__device__ __forceinline__ u16 f2bf(float v) {
    unsigned b = __float_as_uint(v);
    b += 0x7FFF + ((b >> 16) & 1);
    return (u16)(b >> 16);
}
__device__ __forceinline__ float bf2f(u16 h) {
    return __uint_as_float(((unsigned)h) << 16);
}
__device__ __forceinline__ int tri_base(int i) { return (i * (2 * DIM - 1 - i)) >> 1; }
__device__ __forceinline__ void store_bf(u16* oh, u16* ol, int idx, float v, bool act) {
    u16 h = f2bf(v);
    u16 l = f2bf(v - bf2f(h));
    if (act) { oh[idx] = h; ol[idx] = l; }
}

// ==== Phase 1: Q-less G=32 chain (R15-verified, verbatim) ====
__global__ __launch_bounds__(64, 1)
void chain7(const float* __restrict__ th_all,
            u16* __restrict__ MhW, u16* __restrict__ MlW)
{
    __shared__ __align__(16) float csx[992 + 32 * 64];  // 12.2 KB

    const int lane = threadIdx.x;
    const int head = blockIdx.x & 63;        // XCD = head%8, producer+consumer
    const int s    = blockIdx.x >> 6;
    const int a0 = C_A0[s], j0 = C_J0[s], nj = C_NJ[s], n = C_N[s];
    const bool intra = C_INTRA[s] != 0;
    const float* __restrict__ th = th_all + head * NROT;
    u16* __restrict__ oh = MhW + (size_t)head * MHEAD7 + C_OFF[s];
    u16* __restrict__ ol = MlW + (size_t)head * MHEAD7 + C_OFF[s];
    const bool cact = lane < n;
    const int ne = 32 * nj;
    const int d1 = j0 - a0 - 1;

    float thx[16];
    #pragma unroll
    for (int it = 0; it < 16; ++it) {
        if (it * 64 < ne) {
            int e = lane + it * 64;
            int t = e & 31, r = e >> 5;
            thx[it] = th[tri_base(a0 + t) + d1 + r - t];
        }
    }
    float thi[8];
    #pragma unroll
    for (int it = 0; it < 8; ++it) {
        int e = lane + it * 64;
        if (intra && e < 496) {
            int t1 = 0, rem = e;
            while (rem >= 31 - t1) { rem -= 31 - t1; ++t1; }
            thi[it] = th[tri_base(a0 + t1) + rem];
        }
    }
    #pragma unroll
    for (int it = 0; it < 16; ++it) {
        if (it * 64 < ne) {
            int e = lane + it * 64;
            float sn, cn; sincos_poly(thx[it], sn, cn);
            csx[992 + 2 * e] = cn; csx[992 + 2 * e + 1] = sn;
        }
    }
    #pragma unroll
    for (int it = 0; it < 8; ++it) {
        int e = lane + it * 64;
        if (intra && e < 496) {
            float sn, cn; sincos_poly(thi[it], sn, cn);
            csx[2 * e] = cn; csx[2 * e + 1] = sn;
        }
    }
    __syncthreads();

    float p[32];
    #pragma unroll
    for (int t = 0; t < 32; ++t) p[t] = (lane == t) ? 1.0f : 0.0f;

    if (intra) {                             // 496 pivot-pivot rotations
        f4 cc; int idx = 0;
        #pragma unroll
        for (int t1 = 0; t1 < 31; ++t1) {
            #pragma unroll
            for (int t2 = t1 + 1; t2 < 32; ++t2) {
                float c, sn;
                if ((idx & 1) == 0) { cc = *(const f4*)&csx[2 * idx]; c = cc.x; sn = cc.y; }
                else                { c = cc.z; sn = cc.w; }
                float pa = p[t1];
                p[t1] = fmaf(c, pa,    sn * p[t2]);
                p[t2] = fmaf(c, p[t2], -(sn * pa));
                ++idx;
            }
        }
    }

    if (nj > 0) {
        const float* cs = csx + 992;
        const int jv = lane - 32;
        #pragma unroll 2
        for (int r = 0; r < nj; ++r) {
            const f4* c4 = (const f4*)(cs + r * 64);
            f4 q[16];
            #pragma unroll
            for (int i = 0; i < 16; ++i) q[i] = c4[i];
            float v = (r == jv) ? 1.0f : 0.0f;
            #pragma unroll
            for (int t = 0; t < 32; t += 2) {
                f4 qq = q[t >> 1];
                { float pv = p[t];     float nv = fmaf(qq.x, v, -(qq.y * pv));
                  p[t]     = fmaf(qq.y, v, qq.x * pv); v = nv; }
                { float pv = p[t + 1]; float nv = fmaf(qq.z, v, -(qq.w * pv));
                  p[t + 1] = fmaf(qq.w, v, qq.z * pv); v = nv; }
            }
            store_bf(oh, ol, (32 + r) * n + lane, v, cact);
        }
    }

    #pragma unroll
    for (int t = 0; t < 32; ++t)
        store_bf(oh, ol, t * n + lane, p[t], cact);
}

// ==== Phase 2: compose with M bulk-loaded to LDS (one exposure, all-LDS segs) ====
__global__ __launch_bounds__(512, 1)
void compose_lds(const u16* __restrict__ MhA, const u16* __restrict__ MlA,
                 float* __restrict__ out)
{
    __shared__ u16 Msw[51200];           // all 7 segments, swizzled (102400 B)
    __shared__ u16 Ah[32][KAC];          // 8704 B
    __shared__ u16 Al[32][KAC];          // 8704 B

    const int tid  = threadIdx.x;
    const int lane = tid & 63;
    const int w    = tid >> 6;
    const int head = blockIdx.x & 63;    // all 4 quarters -> same XCD as producer
    const int q    = blockIdx.x >> 6;
    const u16* __restrict__ Mh = MhA + (size_t)head * MHEAD7;
    const u16* __restrict__ Ml = MlA + (size_t)head * MHEAD7;

    // ---- bulk M load: coalesced 16B chunks, XOR-granule swizzle per row ----
    #pragma unroll 1
    for (int s = 0; s < NSEG; ++s) {
        const int n = C_N[s];
        const int lsh = (n == 32) ? 2 : 3;           // granules per row = n/8
        const int msk = (1 << lsh) - 1;
        const int nch = (n * n) >> 3;                // 16B chunks per array
        const u16* gh = Mh + C_OFF[s];
        const u16* gl = Ml + C_OFF[s];
        u16* lb = Msw + C_LB[s];
        const int nn = n * n;
        for (int ch = tid; ch < nch; ch += 512) {
            int r  = ch >> lsh;
            int kb = ch & msk;
            int dst = r * n + (((kb ^ (r & msk)) & msk) << 3);
            *(uint4*)&lb[dst]      = *(const uint4*)&gh[ch << 3];
            *(uint4*)&lb[nn + dst] = *(const uint4*)&gl[ch << 3];
        }
    }
    __syncthreads();

    // ---- A init: embedded M0 slice (seg 0, n=64) for this 32-col quarter ----
    for (int i = tid; i < 32 * KAC; i += 512) {
        int c = i / KAC, k = i - c * KAC;
        int cg = q * 32 + c;
        u16 h = 0, l = 0;
        if (k < 64) {
            if (cg < 64) {
                int idx = k * 64 + ((((cg >> 3) ^ (k & 7)) & 7) << 3) + (cg & 7);
                h = Msw[idx]; l = Msw[4096 + idx];
            }
        } else if (k < 128) {
            h = (k == cg) ? (u16)0x3F80 : (u16)0;
        }
        Ah[c][k] = h; Al[c][k] = l;
    }
    __syncthreads();

    // ---- 6 serial MFMA composes, all operands in LDS ----
    const int fr = lane & 15;
    const int fk = (lane >> 4) * 8;
    const int r4 = (lane >> 4) * 4;

    #pragma unroll 1
    for (int s = 1; s < NSEG; ++s) {
        const int a0 = C_A0[s], j0 = C_J0[s], n = C_N[s], LB = C_LB[s];
        const int lsh = (n == 32) ? 2 : 3;
        const int gmsk = (1 << lsh) - 1;
        const int nn = n * n;
        const int nrt = n >> 4;
        const bool act = w < nrt * 2;
        const int rt = w >> 1, ct = w & 1;

        f4 acc = {0, 0, 0, 0};
        if (act) {
            const int rA = rt * 16 + fr;
            const int c  = ct * 16 + fr;
            auto mload = [&](int kc, bf8& mh, bf8& ml) {
                int idx = LB + rA * n + ((((kc >> 3) ^ (rA & gmsk)) & gmsk) << 3);
                mh = *(const bf8*)&Msw[idx];
                ml = *(const bf8*)&Msw[idx + nn];
            };
            bf8 mh0, ml0;
            mload(fk, mh0, ml0);
            bf8 bh0 = *(const bf8*)&Ah[c][a0 + fk];
            bf8 bl0 = *(const bf8*)&Al[c][a0 + fk];
            acc = __builtin_amdgcn_mfma_f32_16x16x32_bf16(mh0, bh0, acc, 0, 0, 0);
            acc = __builtin_amdgcn_mfma_f32_16x16x32_bf16(mh0, bl0, acc, 0, 0, 0);
            acc = __builtin_amdgcn_mfma_f32_16x16x32_bf16(ml0, bh0, acc, 0, 0, 0);
            acc = __builtin_amdgcn_mfma_f32_16x16x32_bf16(ml0, bl0, acc, 0, 0, 0);
            if (n == 64) {
                bf8 mh1, ml1;
                mload(32 + fk, mh1, ml1);
                bf8 bh1 = *(const bf8*)&Ah[c][j0 + fk];
                bf8 bl1 = *(const bf8*)&Al[c][j0 + fk];
                acc = __builtin_amdgcn_mfma_f32_16x16x32_bf16(mh1, bh1, acc, 0, 0, 0);
                acc = __builtin_amdgcn_mfma_f32_16x16x32_bf16(mh1, bl1, acc, 0, 0, 0);
                acc = __builtin_amdgcn_mfma_f32_16x16x32_bf16(ml1, bh1, acc, 0, 0, 0);
                acc = __builtin_amdgcn_mfma_f32_16x16x32_bf16(ml1, bl1, acc, 0, 0, 0);
            }
        }
        __syncthreads();                 // all reads of old A complete (lgkm only)

        if (act) {
            const int rowq = rt * 16 + r4;
            const int rg = (rowq < 32) ? (a0 + rowq) : (j0 + rowq - 32);
            const int c  = ct * 16 + fr;
            float v0 = acc[0], v1 = acc[1], v2 = acc[2], v3 = acc[3];
            u16 h0 = f2bf(v0), h1 = f2bf(v1), h2 = f2bf(v2), h3 = f2bf(v3);
            u16 l0 = f2bf(v0 - bf2f(h0)), l1 = f2bf(v1 - bf2f(h1));
            u16 l2 = f2bf(v2 - bf2f(h2)), l3 = f2bf(v3 - bf2f(h3));
            ushort4 hv; hv.x = h0; hv.y = h1; hv.z = h2; hv.w = h3;
            ushort4 lv; lv.x = l0; lv.y = l1; lv.z = l2; lv.w = l3;
            *(ushort4*)&Ah[c][rg] = hv;
            *(ushort4*)&Al[c][rg] = lv;
        }
        __syncthreads();                 // new A visible
    }

    // ---- output: Q = Ah + Al ----
    {
        float* o = out + (size_t)head * (DIM * DIM) + q * 32;
        for (int i = tid; i < 32 * DIM; i += 512) {
            int c = i & 31, r = i >> 5;
            o[r * DIM + c] = bf2f(Ah[c][r]) + bf2f(Al[c][r]);
        }
    }
}

// ==== Fallback: monolithic Q-in-LDS chain (R7 structure), tiny-ws only ====
struct Row8 { f4 q0, q1, q2, q3; };
__device__ __forceinline__ void ldrow_u(Row8& R, const float* p) {
    const f4* c4 = (const f4*)p;
    R.q0 = c4[0]; R.q1 = c4[1]; R.q2 = c4[2]; R.q3 = c4[3];
}
#define QA(r, c) Q[(r)][ (c) ^ ((r) & 31) ]
#define ROTP(c, s, T, v) { float pt = p[T]; p[T] = fmaf((c), pt, (s) * (v)); \
                           (v) = fmaf((c), (v), -((s) * pt)); }
__device__ __forceinline__ void rot8q(const Row8& r, float p[8], float& v) {
    ROTP(r.q0.x, r.q0.y, 0, v) ROTP(r.q0.z, r.q0.w, 1, v)
    ROTP(r.q1.x, r.q1.y, 2, v) ROTP(r.q1.z, r.q1.w, 3, v)
    ROTP(r.q2.x, r.q2.y, 4, v) ROTP(r.q2.z, r.q2.w, 5, v)
    ROTP(r.q3.x, r.q3.y, 6, v) ROTP(r.q3.z, r.q3.w, 7, v)
}

__global__ __launch_bounds__(64, 1)
void chain_mono(const float* __restrict__ th_all, float* __restrict__ outp)
{
    __shared__ float Q[DIM][64];
    __shared__ __align__(16) float csx[56 + CSROWS * 16];

    const int lane = threadIdx.x;
    const int head = blockIdx.x & 63;
    const int cb   = blockIdx.x >> 6;
    const int col_glob = cb * 64 + lane;
    const float* __restrict__ th = th_all + head * NROT;

    for (int r = 0; r < DIM; ++r)
        QA(r, lane) = (r == col_glob) ? 1.0f : 0.0f;

    #pragma unroll 1
    for (int g = 0; g < 16; ++g) {
        const int a0  = 8 * g;
        const int ntr = 120 - a0;
        float p[8];
        const int nsub = (ntr > CSROWS) ? 2 : 1;
        #pragma unroll 1
        for (int sub = 0; sub < nsub; ++sub) {
            const int r0 = sub * CSROWS;
            const int nr = (ntr - r0) < CSROWS ? (ntr - r0) : CSROWS;
            const int ne = 8 * nr;
            __syncthreads();
            float thx[8];
            #pragma unroll
            for (int it = 0; it < 8; ++it) {
                if (it * 64 < ne) {
                    int e = lane + it * 64;
                    int t = e & 7, jr = r0 + (e >> 3);
                    thx[it] = th[tri_base(a0 + t) + jr + 7 - t];
                }
            }
            float thi = 0.0f;
            if (sub == 0 && lane < 28) {
                int t1 = 0, rem = lane;
                while (rem >= 7 - t1) { rem -= 7 - t1; ++t1; }
                int t2 = t1 + 1 + rem;
                thi = th[tri_base(a0 + t1) + (t2 - t1 - 1)];
            }
            #pragma unroll
            for (int it = 0; it < 8; ++it) {
                if (it * 64 < ne) {
                    int e = lane + it * 64;
                    float sn, cn; sincos_poly(thx[it], sn, cn);
                    csx[56 + 2 * e] = cn; csx[56 + 2 * e + 1] = sn;
                }
            }
            if (sub == 0 && lane < 28) {
                float sn, cn; sincos_poly(thi, sn, cn);
                csx[2 * lane] = cn; csx[2 * lane + 1] = sn;
            }
            __syncthreads();

            if (sub == 0) {
                #pragma unroll
                for (int t = 0; t < 8; ++t) p[t] = QA(a0 + t, lane);
                int idx = 0;
                #pragma unroll
                for (int t1 = 0; t1 < 8; ++t1) {
                    #pragma unroll
                    for (int t2 = t1 + 1; t2 < 8; ++t2) {
                        float c = csx[2 * idx], sn = csx[2 * idx + 1];
                        float pa = p[t1];
                        p[t1] = fmaf(c, pa,    sn * p[t2]);
                        p[t2] = fmaf(c, p[t2], -(sn * pa));
                        ++idx;
                    }
                }
            }
            if (nr > 0) {
                const float* cs = csx + 56;
                const int base = a0 + 8 + r0;
                Row8 A0, A1, B0, B1;
                float vA0, vA1, vB0, vB1;
                auto ldpair = [&](Row8& R, float& v, int r) {
                    ldrow_u(R, cs + 16 * r);
                    v = QA(base + r, lane);
                };
                ldpair(A0, vA0, 0); ldpair(A1, vA1, 1);
                #pragma unroll 1
                for (int r = 0; r < nr; r += 4) {
                    ldpair(B0, vB0, r + 2); ldpair(B1, vB1, r + 3);
                    rot8q(A0, p, vA0); rot8q(A1, p, vA1);
                    QA(base + r, lane)     = vA0;
                    QA(base + r + 1, lane) = vA1;
                    if (r + 4 < nr) { ldpair(A0, vA0, r + 4); ldpair(A1, vA1, r + 5); }
                    rot8q(B0, p, vB0); rot8q(B1, p, vB1);
                    QA(base + r + 2, lane) = vB0;
                    QA(base + r + 3, lane) = vB1;
                }
            }
        }
        #pragma unroll
        for (int t = 0; t < 8; ++t) QA(a0 + t, lane) = p[t];
    }

    __syncthreads();
    float* o = outp + head * (DIM * DIM) + col_glob;
    #pragma unroll 1
    for (int r = 0; r < DIM; ++r) o[r * DIM] = QA(r, lane);
}

extern "C" void kernel_launch(void* const* d_in, const int* in_sizes, int n_in,
                              void* d_out, int out_size, void* d_ws, size_t ws_size,
                              hipStream_t stream) {
    const float* thetas = (const float*)d_in[0];
    float* out = (float*)d_out;
    const size_t need = (size_t)NHEAD * MHEAD7 * 2 * sizeof(u16);  // 6.55 MB

    if (ws_size >= need) {
        u16* MhW = (u16*)d_ws;
        u16* MlW = MhW + (size_t)NHEAD * MHEAD7;
        chain7<<<dim3(NSEG * NHEAD), dim3(64), 0, stream>>>(thetas, MhW, MlW);
        compose_lds<<<dim3(4 * NHEAD), dim3(512), 0, stream>>>(MhW, MlW, out);
    } else {
        chain_mono<<<dim3(2 * NHEAD), dim3(64), 0, stream>>>(thetas, out);
    }
}